// Round 1
// baseline (15995.526 us; speedup 1.0000x reference)
//
#include <hip/hip_runtime.h>

#define NN 10000
#define NE 160000
#define NG 64
#define NT 5
#define NF 75
#define NL 4
#define LOG17 2.8332133f  /* log(17.0) */

// ---------------------------------------------------------------- utilities
__global__ __launch_bounds__(256) void k_init_h(const float* __restrict__ x,
    const float* __restrict__ W, const float* __restrict__ b, float* __restrict__ h){
  int i = blockIdx.x*256 + threadIdx.x;
  if (i >= NN*NF) return;
  int n = i / NF, f = i - n*NF;
  h[i] = x[2*n]*W[f] + x[2*n+1]*W[NF+f] + b[f];
}

__global__ __launch_bounds__(256) void k_count(const int* __restrict__ ei, int* __restrict__ cnt){
  int e = blockIdx.x*256 + threadIdx.x;
  if (e < NE) atomicAdd(&cnt[ei[NE + e]], 1);   // row 1 = dst
}

__global__ __launch_bounds__(1024) void k_scan(const int* __restrict__ cnt,
    int* __restrict__ off, int* __restrict__ cur){
  __shared__ int buf[1024];
  __shared__ int carry;
  int tid = threadIdx.x;
  if (tid == 0) carry = 0;
  __syncthreads();
  for (int base = 0; base < NN; base += 1024){
    int i = base + tid;
    int v = (i < NN) ? cnt[i] : 0;
    buf[tid] = v;
    __syncthreads();
    for (int d = 1; d < 1024; d <<= 1){
      int t = (tid >= d) ? buf[tid - d] : 0;
      __syncthreads();
      buf[tid] += t;
      __syncthreads();
    }
    int c = carry;
    if (i < NN){ int ex = c + buf[tid] - v; off[i] = ex; cur[i] = ex; }
    int tot = buf[1023];
    __syncthreads();
    if (tid == 0) carry = c + tot;
    __syncthreads();
  }
  if (tid == 0) off[NN] = NE;
}

__global__ __launch_bounds__(256) void k_scatter(const int* __restrict__ ei,
    int* __restrict__ cur, int* __restrict__ csr){
  int e = blockIdx.x*256 + threadIdx.x;
  if (e < NE){
    int d = ei[NE + e];
    int p = atomicAdd(&cur[d], 1);
    csr[p] = ei[e];   // src node
  }
}

// ------------------------------------------- fused message-MLP + aggregation
// block = (node n, tower t); 128 threads; threads 0..74 own output feature f.
// m[e,f] = (h[n] @ Wtop)[f] + (h[src_e] @ Wbot)[f] + preb[f]
// Wtop half computed once per node (per-dst term is edge-invariant).
__global__ __launch_bounds__(128) void k_msg_agg(
    const float* __restrict__ h, const int* __restrict__ off, const int* __restrict__ csr,
    const float* __restrict__ preW, const float* __restrict__ preb,
    float* __restrict__ agg, int l){
  __shared__ float Wb[75*96];       // row f: 24 float4 chunks, XOR-swizzled
  __shared__ float evn[80];
  __shared__ float ev8[8*80];
  __shared__ int slds[8];
  int tid = threadIdx.x;
  int b = blockIdx.x;
  int n = b / NT, t = b - n*NT;
  const float* Wg = preW + (size_t)(l*NT + t)*150*75;

  for (int i = tid; i < 75*96; i += 128) Wb[i] = 0.f;
  if (tid < 80) evn[tid] = (tid < 75) ? h[n*75 + tid] : 0.f;
  __syncthreads();
  // stage bottom half of W (c in [75,150)) transposed + swizzled
  for (int i = tid; i < 75*75; i += 128){
    int cb = i / 75, f = i - cb*75;
    int ch = cb >> 2, j = cb & 3;
    Wb[f*96 + (((ch ^ (f & 7)) << 2) + j)] = Wg[(75 + cb)*75 + f];
  }
  __syncthreads();

  int e0 = off[n], e1 = off[n+1];
  float base = 0.f, sum = 0.f, sq = 0.f, mn = 3.4e38f, mx = -3.4e38f;
  if (tid < 75){
    base = preb[(l*NT + t)*75 + tid];
    for (int c = 0; c < 75; ++c) base += Wg[c*75 + tid] * evn[c];  // coalesced, L2-hot
  }

  for (int k0 = e0; k0 < e1; k0 += 8){
    __syncthreads();
    if (tid < 8){
      int k = k0 + tid;
      slds[tid] = csr[(k < e1) ? k : (e1 - 1)];
    }
    __syncthreads();
    for (int i = tid; i < 8*80; i += 128){
      int e = i / 80, c = i - e*80;
      ev8[i] = (c < 75) ? h[slds[e]*75 + c] : 0.f;
    }
    __syncthreads();
    if (tid < 75){
      float dote[8];
      #pragma unroll
      for (int e = 0; e < 8; ++e) dote[e] = 0.f;
      const float* wrow = &Wb[tid*96];
      int fx = (tid & 7) << 2;
      #pragma unroll
      for (int ch = 0; ch < 19; ++ch){
        float4 w = *reinterpret_cast<const float4*>(&wrow[(ch << 2) ^ fx]);
        #pragma unroll
        for (int e = 0; e < 8; ++e){
          float4 p = *reinterpret_cast<const float4*>(&ev8[e*80 + (ch << 2)]);
          dote[e] += w.x*p.x + w.y*p.y + w.z*p.z + w.w*p.w;
        }
      }
      int rem = e1 - k0;
      #pragma unroll
      for (int e = 0; e < 8; ++e){
        if (e < rem){
          float m = base + dote[e];
          sum += m; sq += m*m;
          mn = fminf(mn, m); mx = fmaxf(mx, m);
        }
      }
    }
  }
  if (tid < 75){
    int deg = e1 - e0;
    float d = (float)(deg > 0 ? deg : 1);
    float mean = sum / d;
    float var = sq / d - mean*mean;
    float sd = sqrtf(fmaxf(var, 0.f) + 1e-5f);
    if (deg == 0){ mn = 0.f; mx = 0.f; }
    float* a = agg + (size_t)(n*NT + t)*300;
    a[tid] = mean; a[75+tid] = mn; a[150+tid] = mx; a[225+tid] = sd;
  }
}

// --------------------------------------- post-MLP (975->15 per tower) + lin
__global__ __launch_bounds__(256) void k_post_lin(
    const float* __restrict__ h, const float* __restrict__ agg, const int* __restrict__ off,
    const float* __restrict__ postW, const float* __restrict__ postb,
    const float* __restrict__ linW, const float* __restrict__ linb,
    float* __restrict__ out2, int l){
  __shared__ float invec[5*976];
  __shared__ float h2l[80];
  int tid = threadIdx.x;
  int n = blockIdx.x;
  int deg = off[n+1] - off[n];
  float d = (float)(deg > 0 ? deg : 1);
  float logd = logf(d + 1.f);
  float amp = logd / LOG17;
  float att = LOG17 / logd;
  const float* an = agg + (size_t)n*NT*300;
  for (int i = tid; i < 5*976; i += 256){
    int t = i / 976, c = i - t*976;
    float v = 0.f;
    if (c < 75)       v = h[n*75 + c];
    else if (c < 375) v = an[t*300 + (c - 75)];
    else if (c < 675) v = an[t*300 + (c - 375)] * amp;
    else if (c < 975) v = an[t*300 + (c - 675)] * att;
    invec[i] = v;
  }
  __syncthreads();
  int wv = tid >> 6, lane = tid & 63;
  for (int pass = 0; pass < 19; ++pass){
    int o = pass*4 + wv;
    if (o < 75){
      int t = o / 15, f2 = o - t*15;
      const float* wp = postW + (size_t)(l*NT + t)*975*15 + f2;
      const float* iv = &invec[t*976];
      float part = 0.f;
      for (int c = lane; c < 975; c += 64)
        part += iv[c] * wp[(size_t)c*15];
      #pragma unroll
      for (int s = 32; s > 0; s >>= 1) part += __shfl_xor(part, s);
      if (lane == 0) h2l[o] = part + postb[(l*NT + t)*15 + f2];
    }
  }
  __syncthreads();
  for (int pass = 0; pass < 19; ++pass){
    int o = pass*4 + wv;
    if (o < 75){
      float part = 0.f;
      for (int c = lane; c < 75; c += 64)
        part += h2l[c] * linW[(size_t)(l*75 + c)*75 + o];
      #pragma unroll
      for (int s = 32; s > 0; s >>= 1) part += __shfl_xor(part, s);
      if (lane == 0) out2[n*75 + o] = part + linb[l*75 + o];
    }
  }
}

// -------------------------------------------------------------- batch norm
__global__ __launch_bounds__(256) void k_bn_stats(const float* __restrict__ out2,
    float* __restrict__ bnmu, float* __restrict__ bnrs){
  __shared__ float r1[256], r2[256];
  int f = blockIdx.x, tid = threadIdx.x;
  float s1 = 0.f, s2 = 0.f;
  for (int i = tid; i < NN; i += 256){
    float v = out2[(size_t)i*75 + f];
    s1 += v; s2 += v*v;
  }
  r1[tid] = s1; r2[tid] = s2;
  __syncthreads();
  for (int s = 128; s > 0; s >>= 1){
    if (tid < s){ r1[tid] += r1[tid+s]; r2[tid] += r2[tid+s]; }
    __syncthreads();
  }
  if (tid == 0){
    float mu = r1[0] / (float)NN;
    float var = r2[0] / (float)NN - mu*mu;
    bnmu[f] = mu;
    bnrs[f] = 1.f / sqrtf(var + 1e-5f);
  }
}

__global__ __launch_bounds__(256) void k_bn_apply(const float* __restrict__ out2,
    const float* __restrict__ bnmu, const float* __restrict__ bnrs,
    const float* __restrict__ scale, const float* __restrict__ bias,
    float* __restrict__ h, int l){
  int i = blockIdx.x*256 + threadIdx.x;
  if (i >= NN*75) return;
  int f = i % 75;
  float v = (out2[i] - bnmu[f]) * bnrs[f] * scale[l*75 + f] + bias[l*75 + f];
  h[i] = fmaxf(v, 0.f);
}

// ------------------------------------------------------------ pool + head
__global__ __launch_bounds__(256) void k_pool(const float* __restrict__ h,
    const int* __restrict__ batch, float* __restrict__ pooled){
  int i = blockIdx.x*256 + threadIdx.x;
  if (i >= NN*75) return;
  int n = i / 75, f = i - n*75;
  atomicAdd(&pooled[batch[n]*75 + f], h[i]);
}

__global__ __launch_bounds__(256) void k_head(const float* __restrict__ pooled,
    const float* __restrict__ W1, const float* __restrict__ b1,
    const float* __restrict__ W2, const float* __restrict__ b2,
    const float* __restrict__ W3, const float* __restrict__ b3,
    float* __restrict__ out){
  __shared__ float pl[64*75];
  __shared__ float w1[75*50];
  __shared__ float z1[64*50];
  __shared__ float w2[50*25];
  __shared__ float z2[64*25];
  __shared__ float w3[25];
  __shared__ float bb1[50], bb2[25];
  int tid = threadIdx.x;
  for (int i = tid; i < 64*75; i += 256) pl[i] = pooled[i];
  for (int i = tid; i < 75*50; i += 256) w1[i] = W1[i];
  for (int i = tid; i < 50*25; i += 256) w2[i] = W2[i];
  if (tid < 25) w3[tid] = W3[tid];
  if (tid < 50) bb1[tid] = b1[tid];
  if (tid < 25) bb2[tid] = b2[tid];
  __syncthreads();
  for (int o = tid; o < 64*50; o += 256){
    int g = o / 50, j = o - g*50;
    float acc = bb1[j];
    for (int c = 0; c < 75; ++c) acc += pl[g*75 + c] * w1[c*50 + j];
    z1[o] = fmaxf(acc, 0.f);
  }
  __syncthreads();
  for (int o = tid; o < 64*25; o += 256){
    int g = o / 25, j = o - g*25;
    float acc = bb2[j];
    for (int c = 0; c < 50; ++c) acc += z1[g*50 + c] * w2[c*25 + j];
    z2[o] = fmaxf(acc, 0.f);
  }
  __syncthreads();
  if (tid < 64){
    float acc = b3[0];
    for (int c = 0; c < 25; ++c) acc += z2[tid*25 + c] * w3[c];
    out[tid] = acc;
  }
}

// ---------------------------------------------------------------- launcher
extern "C" void kernel_launch(void* const* d_in, const int* in_sizes, int n_in,
                              void* d_out, int out_size, void* d_ws, size_t ws_size,
                              hipStream_t stream){
  const float* x     = (const float*)d_in[0];
  const int*   ei    = (const int*)  d_in[1];
  const int*   batch = (const int*)  d_in[2];
  const float* plW   = (const float*)d_in[3];
  const float* plb   = (const float*)d_in[4];
  const float* preW  = (const float*)d_in[5];
  const float* preb  = (const float*)d_in[6];
  const float* postW = (const float*)d_in[7];
  const float* postb = (const float*)d_in[8];
  const float* linW  = (const float*)d_in[9];
  const float* linb  = (const float*)d_in[10];
  const float* bns   = (const float*)d_in[11];
  const float* bnb   = (const float*)d_in[12];
  const float* W1    = (const float*)d_in[13];
  const float* b1    = (const float*)d_in[14];
  const float* W2    = (const float*)d_in[15];
  const float* b2    = (const float*)d_in[16];
  const float* W3    = (const float*)d_in[17];
  const float* b3    = (const float*)d_in[18];
  float* out = (float*)d_out;

  // workspace layout (~64 MiB total)
  float* h      = (float*)d_ws;
  float* out2   = h + 750000;
  float* agg    = out2 + 750000;                 // [NN][NT][300] f32 = 60 MB
  float* pooled = agg + (size_t)15000000;
  float* bnmu   = pooled + 4800;
  float* bnrs   = bnmu + 75;
  int* cnt = (int*)(bnrs + 75);
  int* off = cnt + NN;
  int* cur = off + NN + 1;
  int* csr = cur + NN;

  hipMemsetAsync(cnt, 0, NN*sizeof(int), stream);
  k_init_h<<<(NN*NF + 255)/256, 256, 0, stream>>>(x, plW, plb, h);
  k_count<<<(NE + 255)/256, 256, 0, stream>>>(ei, cnt);
  k_scan<<<1, 1024, 0, stream>>>(cnt, off, cur);
  k_scatter<<<(NE + 255)/256, 256, 0, stream>>>(ei, cur, csr);

  for (int l = 0; l < NL; ++l){
    k_msg_agg<<<NN*NT, 128, 0, stream>>>(h, off, csr, preW, preb, agg, l);
    k_post_lin<<<NN, 256, 0, stream>>>(h, agg, off, postW, postb, linW, linb, out2, l);
    k_bn_stats<<<75, 256, 0, stream>>>(out2, bnmu, bnrs);
    k_bn_apply<<<(NN*NF + 255)/256, 256, 0, stream>>>(out2, bnmu, bnrs, bns, bnb, h, l);
  }

  hipMemsetAsync(pooled, 0, 4800*sizeof(float), stream);
  k_pool<<<(NN*NF + 255)/256, 256, 0, stream>>>(h, batch, pooled);
  k_head<<<1, 256, 0, stream>>>(pooled, W1, b1, W2, b2, W3, b3, out);
}

// Round 2
// 1111.886 us; speedup vs baseline: 14.3859x; 14.3859x over previous
//
#include <hip/hip_runtime.h>

#define NN 10000
#define NE 160000
#define NG 64
#define NT 5
#define NF 75
#define NL 4
#define LOG17 2.8332133f  /* log(17.0) */
#define ROW1 752          /* out1 row stride (B 375 | base 375 | pad) */
#define WCN 832           /* Wcat padded cols: B 375 | base 375 | y0 75 | pad */

// ---------------------------------------------------------------- setup
__global__ __launch_bounds__(256) void k_init_h(const float* __restrict__ x,
    const float* __restrict__ W, const float* __restrict__ b, float* __restrict__ h){
  int i = blockIdx.x*256 + threadIdx.x;
  if (i >= NN*NF) return;
  int n = i / NF, f = i - n*NF;
  h[i] = x[2*n]*W[f] + x[2*n+1]*W[NF+f] + b[f];
}

__global__ __launch_bounds__(256) void k_count(const int* __restrict__ ei, int* __restrict__ cnt){
  int e = blockIdx.x*256 + threadIdx.x;
  if (e < NE) atomicAdd(&cnt[ei[NE + e]], 1);   // row 1 = dst
}

__global__ __launch_bounds__(1024) void k_scan(const int* __restrict__ cnt,
    int* __restrict__ off, int* __restrict__ cur){
  __shared__ int buf[1024];
  __shared__ int carry;
  int tid = threadIdx.x;
  if (tid == 0) carry = 0;
  __syncthreads();
  for (int base = 0; base < NN; base += 1024){
    int i = base + tid;
    int v = (i < NN) ? cnt[i] : 0;
    buf[tid] = v;
    __syncthreads();
    for (int d = 1; d < 1024; d <<= 1){
      int t = (tid >= d) ? buf[tid - d] : 0;
      __syncthreads();
      buf[tid] += t;
      __syncthreads();
    }
    int c = carry;
    if (i < NN){ int ex = c + buf[tid] - v; off[i] = ex; cur[i] = ex; }
    int tot = buf[1023];
    __syncthreads();
    if (tid == 0) carry = c + tot;
    __syncthreads();
  }
  if (tid == 0) off[NN] = NE;
}

__global__ __launch_bounds__(256) void k_scatter(const int* __restrict__ ei,
    int* __restrict__ cur, int* __restrict__ csr){
  int e = blockIdx.x*256 + threadIdx.x;
  if (e < NE){
    int d = ei[NE + e];
    int p = atomicAdd(&cur[d], 1);
    csr[p] = ei[e];   // src node
  }
}

// Wcat[l][75][832]: cols 0..374 = Wbot (preW rows 75+c), 375..749 = Wtop (rows c),
// 750..824 = postW rows 0..74 (y0), rest 0.
__global__ __launch_bounds__(256) void k_buildWcat(const float* __restrict__ preW,
    const float* __restrict__ postW, float* __restrict__ Wcat){
  int idx = blockIdx.x*256 + threadIdx.x;
  if (idx >= NL*75*WCN) return;
  int l = idx / (75*WCN);
  int rem = idx - l*75*WCN;
  int c = rem / WCN, j = rem - c*WCN;
  float v = 0.f;
  if (j < 375){
    int t = j/75, f = j - t*75;
    v = preW[(size_t)((l*NT + t)*150 + 75 + c)*75 + f];
  } else if (j < 750){
    int jj = j - 375; int t = jj/75, f = jj - t*75;
    v = preW[(size_t)((l*NT + t)*150 + c)*75 + f];
  } else if (j < 825){
    int jj = j - 750; int t = jj/15, f2 = jj - t*15;
    v = postW[(size_t)((l*NT + t)*975 + c)*15 + f2];
  }
  Wcat[idx] = v;
}

// W45[l][t][300][48]: col g*15+f2 = postW row (75 + g*300 + c), col f2. pads 0.
__global__ __launch_bounds__(256) void k_buildW45(const float* __restrict__ postW,
    float* __restrict__ W45){
  int idx = blockIdx.x*256 + threadIdx.x;
  if (idx >= NL*NT*300*48) return;
  int l = idx / (NT*300*48);
  int rem = idx - l*NT*300*48;
  int t = rem / (300*48);
  int rem2 = rem - t*300*48;
  int c = rem2 / 48, f48 = rem2 - c*48;
  float v = 0.f;
  if (f48 < 45){
    int g = f48/15, f2 = f48 - g*15;
    v = postW[(size_t)((l*NT + t)*975 + 75 + g*300 + c)*15 + f2];
  }
  W45[idx] = v;
}

// -------------------- GEMM1: out1[B|base] (+preb on base), z <- y0. M=10000,K=75
__global__ __launch_bounds__(256) void k_gemm1(const float* __restrict__ h,
    const float* __restrict__ Wcat, const float* __restrict__ preb,
    float* __restrict__ out1, float* __restrict__ z, int l){
  __shared__ float As[75][68];
  __shared__ float Ws[75][128];
  int tid = threadIdx.x;
  int bid = blockIdx.x;
  int nt = bid / 7, jt = bid - nt*7;
  int n0 = nt*64, j0 = jt*128;

  for (int idx = tid; idx < 64*75; idx += 256){
    int i = idx/75, c = idx - i*75;
    As[c][i] = (n0 + i < NN) ? h[(size_t)n0*75 + idx] : 0.f;
  }
  const float* wg = Wcat + (size_t)l*75*WCN;
  for (int idx = tid; idx < 75*128; idx += 256){
    int c = idx >> 7, j = idx & 127;
    int col = j0 + j;
    Ws[c][j] = (col < WCN) ? wg[(size_t)c*WCN + col] : 0.f;
  }
  __syncthreads();

  int jj = tid >> 4, n4 = tid & 15;
  float acc[4][8];
  #pragma unroll
  for (int i = 0; i < 4; ++i)
    #pragma unroll
    for (int j = 0; j < 8; ++j) acc[i][j] = 0.f;

  for (int c = 0; c < 75; ++c){
    float4 a = *reinterpret_cast<const float4*>(&As[c][n4*4]);
    float4 w0 = *reinterpret_cast<const float4*>(&Ws[c][jj*8]);
    float4 w1 = *reinterpret_cast<const float4*>(&Ws[c][jj*8 + 4]);
    float av[4] = {a.x, a.y, a.z, a.w};
    float wv[8] = {w0.x, w0.y, w0.z, w0.w, w1.x, w1.y, w1.z, w1.w};
    #pragma unroll
    for (int i = 0; i < 4; ++i)
      #pragma unroll
      for (int j = 0; j < 8; ++j) acc[i][j] += av[i]*wv[j];
  }

  #pragma unroll
  for (int i = 0; i < 4; ++i){
    int n = n0 + n4*4 + i;
    if (n >= NN) continue;
    #pragma unroll
    for (int j = 0; j < 8; ++j){
      int col = j0 + jj*8 + j;
      float v = acc[i][j];
      if (col < 375)      out1[(size_t)n*ROW1 + col] = v;
      else if (col < 750) out1[(size_t)n*ROW1 + col] = v + preb[l*375 + (col - 375)];
      else if (col < 825) z[(size_t)n*75 + (col - 750)] = v;
    }
  }
}

// ---- fused aggregate (gather B, combine base) + post-GEMM (K=300,N=45) + scalers
// block = (32-node tile, tower). 128 threads.
__global__ __launch_bounds__(128) void k_aggpost(
    const float* __restrict__ out1, float* __restrict__ z,
    const int* __restrict__ off, const int* __restrict__ csr,
    const float* __restrict__ W45, const float* __restrict__ postb, int l){
  __shared__ float As[60][36];
  __shared__ float Ws[60][64];
  __shared__ float dln[32];
  int tid = threadIdx.x;
  int bid = blockIdx.x;
  int nt = bid / NT, t = bid - nt*NT;
  int n0 = nt*32;

  // ---------- phase A: per-thread gather-aggregate (19 features max)
  int n_loc = tid >> 2, q = tid & 3;
  int n = n0 + n_loc;
  int f0 = q*19;
  int nf = (q == 3) ? 18 : 19;
  float s[19], ss[19], mnv[19], mxv[19];
  #pragma unroll
  for (int j = 0; j < 19; ++j){ s[j]=0.f; ss[j]=0.f; mnv[j]=3.4e38f; mxv[j]=-3.4e38f; }
  int deg = 0; float d = 1.f;
  if (n < NN){
    int e0 = off[n], e1 = off[n+1];
    deg = e1 - e0;
    d = (float)(deg > 0 ? deg : 1);
    for (int k = e0; k < e1; ++k){
      const float* bp = out1 + (size_t)csr[k]*ROW1 + t*75 + f0;
      #pragma unroll
      for (int j = 0; j < 19; ++j){
        if (j < nf){
          float v = bp[j];
          s[j] += v; ss[j] += v*v;
          mnv[j] = fminf(mnv[j], v); mxv[j] = fmaxf(mxv[j], v);
        }
      }
    }
    // finalize into [mean, mn, mx, sd] (reuse arrays)
    const float* basep = out1 + (size_t)n*ROW1 + 375 + t*75 + f0;
    #pragma unroll
    for (int j = 0; j < 19; ++j){
      if (j < nf){
        if (deg > 0){
          float mb = s[j] / d;
          float var = ss[j] / d - mb*mb;
          float bs = basep[j];
          s[j]  = bs + mb;
          ss[j] = sqrtf(fmaxf(var, 0.f) + 1e-5f);
          mnv[j] = bs + mnv[j];
          mxv[j] = bs + mxv[j];
        } else {
          s[j] = 0.f; ss[j] = sqrtf(1e-5f); mnv[j] = 0.f; mxv[j] = 0.f;
        }
      }
    }
    if (q == 0) dln[n_loc] = d;
  }

  // ---------- phase B: GEMM over K=300 in 5 chunks of 60, A staged from regs
  int nq = tid & 7, fg = tid >> 3;      // nodes nq*4..+3, f48 = fg*3..+2
  float acc[4][3];
  #pragma unroll
  for (int i = 0; i < 4; ++i){ acc[i][0]=0.f; acc[i][1]=0.f; acc[i][2]=0.f; }
  const float* wg = W45 + (size_t)(l*NT + t)*300*48;

  for (int ch = 0; ch < 5; ++ch){
    int c0 = ch*60;
    // stage W chunk (col layout: group g at 4*g + e, pad col 3 unused)
    for (int idx = tid; idx < 60*48; idx += 128){
      int cc = idx / 48, f48 = idx - cc*48;
      Ws[cc][(f48/3)*4 + (f48 - (f48/3)*3)] = wg[(size_t)(c0 + cc)*48 + f48];
    }
    // write A rows in [c0, c0+60) from reg stats
    if (n < NN){
      #pragma unroll
      for (int j = 0; j < 19; ++j){
        if (j < nf){
          int f = f0 + j, c;
          c = f;       if (c >= c0 && c < c0+60) As[c - c0][n_loc] = s[j];
          c = 75 + f;  if (c >= c0 && c < c0+60) As[c - c0][n_loc] = mnv[j];
          c = 150 + f; if (c >= c0 && c < c0+60) As[c - c0][n_loc] = mxv[j];
          c = 225 + f; if (c >= c0 && c < c0+60) As[c - c0][n_loc] = ss[j];
        }
      }
    }
    __syncthreads();
    for (int cc = 0; cc < 60; ++cc){
      float4 a = *reinterpret_cast<const float4*>(&As[cc][nq*4]);
      float4 w = *reinterpret_cast<const float4*>(&Ws[cc][fg*4]);
      float av[4] = {a.x, a.y, a.z, a.w};
      #pragma unroll
      for (int i = 0; i < 4; ++i){
        acc[i][0] += av[i]*w.x; acc[i][1] += av[i]*w.y; acc[i][2] += av[i]*w.z;
      }
    }
    __syncthreads();
  }

  // ---------- partials -> LDS, combine with scalers into z
  float* part = &As[0][0];       // [48][36] fits in As region
  #pragma unroll
  for (int e = 0; e < 3; ++e){
    int f48 = fg*3 + e;
    #pragma unroll
    for (int i = 0; i < 4; ++i) part[f48*36 + nq*4 + i] = acc[i][e];
  }
  __syncthreads();
  for (int idx = tid; idx < 32*15; idx += 128){
    int nl = idx / 15, f2 = idx - nl*15;
    int nn = n0 + nl;
    if (nn < NN){
      float dd = dln[nl];
      float logd = logf(dd + 1.f);
      float amp = logd / LOG17, att = LOG17 / logd;
      float g0 = part[f2*36 + nl];
      float g1 = part[(15 + f2)*36 + nl];
      float g2 = part[(30 + f2)*36 + nl];
      size_t zi = (size_t)nn*75 + t*15 + f2;
      z[zi] = z[zi] + g0 + amp*g1 + att*g2 + postb[(l*NT + t)*15 + f2];
    }
  }
}

// -------------------------------- mixing lin: out2 = z @ linW + linb (75x75)
__global__ __launch_bounds__(256) void k_lin(const float* __restrict__ z,
    const float* __restrict__ linW, const float* __restrict__ linb,
    float* __restrict__ out2, int l){
  __shared__ float zs[75][68];
  __shared__ float lw[75][80];
  int tid = threadIdx.x;
  int n0 = blockIdx.x*64;
  for (int idx = tid; idx < 64*75; idx += 256){
    int i = idx/75, c = idx - i*75;
    zs[c][i] = (n0 + i < NN) ? z[(size_t)n0*75 + idx] : 0.f;
  }
  for (int idx = tid; idx < 75*80; idx += 256){
    int c = idx/80, o = idx - c*80;
    lw[c][o] = (o < 75) ? linW[(size_t)l*5625 + c*75 + o] : 0.f;
  }
  __syncthreads();
  int og = tid >> 4, n4 = tid & 15;
  int o0 = og*5;
  float acc[4][5];
  #pragma unroll
  for (int i = 0; i < 4; ++i)
    #pragma unroll
    for (int k = 0; k < 5; ++k) acc[i][k] = 0.f;
  for (int c = 0; c < 75; ++c){
    float4 a = *reinterpret_cast<const float4*>(&zs[c][n4*4]);
    float av[4] = {a.x, a.y, a.z, a.w};
    float wv[5];
    #pragma unroll
    for (int k = 0; k < 5; ++k) wv[k] = lw[c][o0 + k];
    #pragma unroll
    for (int i = 0; i < 4; ++i)
      #pragma unroll
      for (int k = 0; k < 5; ++k) acc[i][k] += av[i]*wv[k];
  }
  #pragma unroll
  for (int i = 0; i < 4; ++i){
    int n = n0 + n4*4 + i;
    if (n >= NN) continue;
    #pragma unroll
    for (int k = 0; k < 5; ++k){
      int o = o0 + k;
      if (o < 75) out2[(size_t)n*75 + o] = acc[i][k] + linb[l*75 + o];
    }
  }
}

// -------------------------------------------------------------- batch norm
__global__ __launch_bounds__(256) void k_bn_stats(const float* __restrict__ out2,
    float* __restrict__ bnmu, float* __restrict__ bnrs){
  __shared__ float r1[256], r2[256];
  int f = blockIdx.x, tid = threadIdx.x;
  float s1 = 0.f, s2 = 0.f;
  for (int i = tid; i < NN; i += 256){
    float v = out2[(size_t)i*75 + f];
    s1 += v; s2 += v*v;
  }
  r1[tid] = s1; r2[tid] = s2;
  __syncthreads();
  for (int s = 128; s > 0; s >>= 1){
    if (tid < s){ r1[tid] += r1[tid+s]; r2[tid] += r2[tid+s]; }
    __syncthreads();
  }
  if (tid == 0){
    float mu = r1[0] / (float)NN;
    float var = r2[0] / (float)NN - mu*mu;
    bnmu[f] = mu;
    bnrs[f] = 1.f / sqrtf(var + 1e-5f);
  }
}

__global__ __launch_bounds__(256) void k_bn_apply(const float* __restrict__ out2,
    const float* __restrict__ bnmu, const float* __restrict__ bnrs,
    const float* __restrict__ scale, const float* __restrict__ bias,
    float* __restrict__ h, int l){
  int i = blockIdx.x*256 + threadIdx.x;
  if (i >= NN*75) return;
  int f = i % 75;
  float v = (out2[i] - bnmu[f]) * bnrs[f] * scale[l*75 + f] + bias[l*75 + f];
  h[i] = fmaxf(v, 0.f);
}

// ------------------------------------------------------------ pool + head
__global__ __launch_bounds__(256) void k_pool(const float* __restrict__ h,
    const int* __restrict__ batch, float* __restrict__ pooled){
  int i = blockIdx.x*256 + threadIdx.x;
  if (i >= NN*75) return;
  int n = i / 75, f = i - n*75;
  atomicAdd(&pooled[batch[n]*75 + f], h[i]);
}

__global__ __launch_bounds__(256) void k_head(const float* __restrict__ pooled,
    const float* __restrict__ W1, const float* __restrict__ b1,
    const float* __restrict__ W2, const float* __restrict__ b2,
    const float* __restrict__ W3, const float* __restrict__ b3,
    float* __restrict__ out){
  __shared__ float pl[64*75];
  __shared__ float w1[75*50];
  __shared__ float z1[64*50];
  __shared__ float w2[50*25];
  __shared__ float z2[64*25];
  __shared__ float w3[25];
  __shared__ float bb1[50], bb2[25];
  int tid = threadIdx.x;
  for (int i = tid; i < 64*75; i += 256) pl[i] = pooled[i];
  for (int i = tid; i < 75*50; i += 256) w1[i] = W1[i];
  for (int i = tid; i < 50*25; i += 256) w2[i] = W2[i];
  if (tid < 25) w3[tid] = W3[tid];
  if (tid < 50) bb1[tid] = b1[tid];
  if (tid < 25) bb2[tid] = b2[tid];
  __syncthreads();
  for (int o = tid; o < 64*50; o += 256){
    int g = o / 50, j = o - g*50;
    float acc = bb1[j];
    for (int c = 0; c < 75; ++c) acc += pl[g*75 + c] * w1[c*50 + j];
    z1[o] = fmaxf(acc, 0.f);
  }
  __syncthreads();
  for (int o = tid; o < 64*25; o += 256){
    int g = o / 25, j = o - g*25;
    float acc = bb2[j];
    for (int c = 0; c < 50; ++c) acc += z1[g*50 + c] * w2[c*25 + j];
    z2[o] = fmaxf(acc, 0.f);
  }
  __syncthreads();
  if (tid < 64){
    float acc = b3[0];
    for (int c = 0; c < 25; ++c) acc += z2[tid*25 + c] * w3[c];
    out[tid] = acc;
  }
}

// ---------------------------------------------------------------- launcher
extern "C" void kernel_launch(void* const* d_in, const int* in_sizes, int n_in,
                              void* d_out, int out_size, void* d_ws, size_t ws_size,
                              hipStream_t stream){
  const float* x     = (const float*)d_in[0];
  const int*   ei    = (const int*)  d_in[1];
  const int*   batch = (const int*)  d_in[2];
  const float* plW   = (const float*)d_in[3];
  const float* plb   = (const float*)d_in[4];
  const float* preW  = (const float*)d_in[5];
  const float* preb  = (const float*)d_in[6];
  const float* postW = (const float*)d_in[7];
  const float* postb = (const float*)d_in[8];
  const float* linW  = (const float*)d_in[9];
  const float* linb  = (const float*)d_in[10];
  const float* bns   = (const float*)d_in[11];
  const float* bnb   = (const float*)d_in[12];
  const float* W1    = (const float*)d_in[13];
  const float* b1    = (const float*)d_in[14];
  const float* W2    = (const float*)d_in[15];
  const float* b2    = (const float*)d_in[16];
  const float* W3    = (const float*)d_in[17];
  const float* b3    = (const float*)d_in[18];
  float* out = (float*)d_out;

  // workspace layout (~43 MB)
  float* h     = (float*)d_ws;                 // 750000
  float* out2  = h + 750000;                   // 750000
  float* z     = out2 + 750000;                // 750000
  float* out1  = z + 750000;                   // 10000*752
  float* Wcat  = out1 + (size_t)NN*ROW1;       // 4*75*832
  float* W45   = Wcat + NL*75*WCN;             // 4*5*300*48
  float* pooled= W45 + NL*NT*300*48;           // 4800
  float* bnmu  = pooled + 4800;
  float* bnrs  = bnmu + 75;
  int* cnt = (int*)(bnrs + 75);
  int* off = cnt + NN;
  int* cur = off + NN + 1;
  int* csr = cur + NN;

  hipMemsetAsync(cnt, 0, NN*sizeof(int), stream);
  k_init_h<<<(NN*NF + 255)/256, 256, 0, stream>>>(x, plW, plb, h);
  k_count<<<(NE + 255)/256, 256, 0, stream>>>(ei, cnt);
  k_scan<<<1, 1024, 0, stream>>>(cnt, off, cur);
  k_scatter<<<(NE + 255)/256, 256, 0, stream>>>(ei, cur, csr);
  k_buildWcat<<<(NL*75*WCN + 255)/256, 256, 0, stream>>>(preW, postW, Wcat);
  k_buildW45<<<(NL*NT*300*48 + 255)/256, 256, 0, stream>>>(postW, W45);

  for (int l = 0; l < NL; ++l){
    k_gemm1<<<157*7, 256, 0, stream>>>(h, Wcat, preb, out1, z, l);
    k_aggpost<<<313*NT, 128, 0, stream>>>(out1, z, off, csr, W45, postb, l);
    k_lin<<<157, 256, 0, stream>>>(z, linW, linb, out2, l);
    k_bn_stats<<<75, 256, 0, stream>>>(out2, bnmu, bnrs);
    k_bn_apply<<<(NN*NF + 255)/256, 256, 0, stream>>>(out2, bnmu, bnrs, bns, bnb, h, l);
  }

  hipMemsetAsync(pooled, 0, 4800*sizeof(float), stream);
  k_pool<<<(NN*NF + 255)/256, 256, 0, stream>>>(h, batch, pooled);
  k_head<<<1, 256, 0, stream>>>(pooled, W1, b1, W2, b2, W3, b3, out);
}